// Round 1
// baseline (34.050 us; speedup 1.0000x reference)
//
#include <hip/hip_runtime.h>
#include <hip/hip_bf16.h>

#define DX 128
#define DH 128
#define HID 512
#define NB 4096
#define ROWS 16
#define OUTC 129   // 128 v cols + 1 div col

typedef __attribute__((ext_vector_type(4))) float f32x4;
typedef __attribute__((ext_vector_type(8))) short bf16x8;

// RNE float -> bf16 (bit pattern in a short)
__device__ inline short f2bf(float f) {
    unsigned u = __float_as_uint(f);
    unsigned r = (u + 0x7fffu + ((u >> 16) & 1u)) >> 16;
    return (short)r;
}

__device__ inline float fast_tanh(float x) {
    // tanh(x) = 1 - 2/(exp(2x)+1); v_exp + v_rcp, handles +-inf correctly
    float e = __expf(2.0f * x);
    float r = __builtin_amdgcn_rcpf(e + 1.0f);
    return 1.0f - 2.0f * r;
}

// -------- prep: c[k] = sum_i W1[i,k]*W2[k,i]; pack W1,W2 to bf16 B-fragment order ---
// W1P layout: [nt(32)][ks(8)][lane(64)][e(8)]  ->  W1[(ks*32 + (l>>4)*8 + e), nt*16 + (l&15)]
// W2P layout: [nt(8)][ks(16)][lane(64)][e(8)]  ->  W2[(ks*32 + (l>>4)*8 + e), nt*16 + (l&15)]
__global__ __launch_bounds__(256) void prep_kernel(
    const float* __restrict__ W1, const float* __restrict__ W2,
    float* __restrict__ c, short* __restrict__ w1p, short* __restrict__ w2p)
{
    int gid = blockIdx.x * 256 + threadIdx.x;  // 0..65535

    if (gid < HID) {
        float acc = 0.f;
        for (int i = 0; i < DX; ++i) acc += W1[i * HID + gid] * W2[gid * DX + i];
        c[gid] = acc;
    }

    for (int i = gid; i < 32 * 8 * 64 * 8; i += 65536) {   // 131072 elems, 2 iters
        int nt = i >> 12;
        int ks = (i >> 9) & 7;
        int l  = (i >> 3) & 63;
        int e  = i & 7;
        int m  = ks * 32 + ((l >> 4) << 3) + e;     // 0..255
        int n  = nt * 16 + (l & 15);                // 0..511
        w1p[i] = f2bf(W1[m * HID + n]);
    }

    if (gid < 8 * 16 * 64 * 8) {                    // 65536 elems
        int i = gid;
        int nt = i >> 13;
        int ks = (i >> 9) & 15;
        int l  = (i >> 3) & 63;
        int e  = i & 7;
        int k  = ks * 32 + ((l >> 4) << 3) + e;     // 0..511
        int n  = nt * 16 + (l & 15);                // 0..127
        w2p[i] = f2bf(W2[k * DX + n]);
    }
}

// -------- main fused kernel: 16 rows per block, 4 waves --------
__global__ __launch_bounds__(256) void cvf_kernel(
    const float* __restrict__ state, const float* __restrict__ h_,
    const float* __restrict__ hn_, const float* __restrict__ tptr,
    const float* __restrict__ gsptr, const float* __restrict__ W1,
    const float* __restrict__ b1, const float* __restrict__ b2,
    const float* __restrict__ c, const short* __restrict__ w1p,
    const short* __restrict__ w2p, float* __restrict__ out)
{
    __shared__ short xb [ROWS][DX  + 8];
    __shared__ short hb [ROWS][DH  + 8];
    __shared__ short hnb[ROWS][DH  + 8];
    __shared__ short ab_h[ROWS][HID + 8];
    __shared__ short ab_n[ROWS][HID + 8];
    __shared__ float divp[2][4][ROWS];

    const int tid  = threadIdx.x;
    const int lane = tid & 63;
    const int w    = tid >> 6;         // wave 0..3
    const int l15  = lane & 15;
    const int l4   = lane >> 4;
    const int row0 = blockIdx.x * ROWS;
    const float t  = tptr[0];
    const float gs = gsptr[0];

    // ---- stage x / h / h_null as bf16 into LDS ----
    {
        int r  = tid >> 4;            // 0..15
        int c0 = (tid & 15) * 8;      // 0..120
        const float* sp = state + (row0 + r) * OUTC + c0;   // x = state[:, :128]
        const float* hp = h_    + (row0 + r) * DH   + c0;
        const float* np = hn_   + (row0 + r) * DH   + c0;
        bf16x8 vx, vh, vn;
        for (int e = 0; e < 8; ++e) {
            vx[e] = f2bf(sp[e]);
            vh[e] = f2bf(hp[e]);
            vn[e] = f2bf(np[e]);
        }
        *(bf16x8*)&xb [r][c0] = vx;
        *(bf16x8*)&hb [r][c0] = vh;
        *(bf16x8*)&hnb[r][c0] = vn;
    }
    __syncthreads();

    // ---- GEMM1: pre = [x|h|t] @ W1 + b1, wave w owns hidden cols [w*128, w*128+128) ----
    f32x4 acc_h[8], acc_n[8];
    {
        f32x4 accx[8];
        for (int nt = 0; nt < 8; ++nt) {
            int k = w * 128 + nt * 16 + l15;
            float base = b1[k] + t * W1[256 * HID + k];   // bias + t-column folded into C
            accx[nt] = (f32x4){base, base, base, base};
        }
        for (int ks = 0; ks < 4; ++ks) {                  // x part: K = 128
            bf16x8 af = *(const bf16x8*)&xb[l15][ks * 32 + l4 * 8];
            for (int nt = 0; nt < 8; ++nt) {
                bf16x8 bf = *(const bf16x8*)&w1p[(((w * 8 + nt) * 8 + ks) * 64 + lane) * 8];
                accx[nt] = __builtin_amdgcn_mfma_f32_16x16x32_bf16(af, bf, accx[nt], 0, 0, 0);
            }
        }
        for (int nt = 0; nt < 8; ++nt) { acc_h[nt] = accx[nt]; acc_n[nt] = accx[nt]; }
        for (int ks = 0; ks < 4; ++ks) {                  // h / h_null part: K = 128
            bf16x8 afh = *(const bf16x8*)&hb [l15][ks * 32 + l4 * 8];
            bf16x8 afn = *(const bf16x8*)&hnb[l15][ks * 32 + l4 * 8];
            for (int nt = 0; nt < 8; ++nt) {
                bf16x8 bf = *(const bf16x8*)&w1p[(((w * 8 + nt) * 8 + 4 + ks) * 64 + lane) * 8];
                acc_h[nt] = __builtin_amdgcn_mfma_f32_16x16x32_bf16(afh, bf, acc_h[nt], 0, 0, 0);
                acc_n[nt] = __builtin_amdgcn_mfma_f32_16x16x32_bf16(afn, bf, acc_n[nt], 0, 0, 0);
            }
        }
    }

    // ---- epilogue A: a = tanh(pre) -> LDS (bf16); div partials (1-a^2)*c[k] ----
    float dph[4] = {0, 0, 0, 0}, dpn[4] = {0, 0, 0, 0};
    for (int nt = 0; nt < 8; ++nt) {
        int k = w * 128 + nt * 16 + l15;                  // D-frag col = lane&15 (m89-verified)
        float ck = c[k];
        for (int q = 0; q < 4; ++q) {
            int r = l4 * 4 + q;                           // D-frag row = (lane>>4)*4 + q
            float a1 = fast_tanh(acc_h[nt][q]);
            float a2 = fast_tanh(acc_n[nt][q]);
            ab_h[r][k] = f2bf(a1);
            ab_n[r][k] = f2bf(a2);
            dph[q] += (1.f - a1 * a1) * ck;
            dpn[q] += (1.f - a2 * a2) * ck;
        }
    }
    // reduce div partials over the 16 lanes sharing l4 (xor only low 4 lane bits)
    for (int q = 0; q < 4; ++q) {
        for (int m = 1; m < 16; m <<= 1) {
            dph[q] += __shfl_xor(dph[q], m, 64);
            dpn[q] += __shfl_xor(dpn[q], m, 64);
        }
    }
    if (l15 == 0) {
        for (int q = 0; q < 4; ++q) {
            divp[0][w][l4 * 4 + q] = dph[q];
            divp[1][w][l4 * 4 + q] = dpn[q];
        }
    }
    __syncthreads();

    // ---- GEMM2: v = a @ W2, wave w owns out cols [w*32, w*32+32) ----
    f32x4 avh[2], avn[2];
    for (int j = 0; j < 2; ++j) { avh[j] = (f32x4){0,0,0,0}; avn[j] = (f32x4){0,0,0,0}; }
    for (int ks = 0; ks < 16; ++ks) {
        bf16x8 afh = *(const bf16x8*)&ab_h[l15][ks * 32 + l4 * 8];
        bf16x8 afn = *(const bf16x8*)&ab_n[l15][ks * 32 + l4 * 8];
        for (int j = 0; j < 2; ++j) {
            bf16x8 bf = *(const bf16x8*)&w2p[(((w * 2 + j) * 16 + ks) * 64 + lane) * 8];
            avh[j] = __builtin_amdgcn_mfma_f32_16x16x32_bf16(afh, bf, avh[j], 0, 0, 0);
            avn[j] = __builtin_amdgcn_mfma_f32_16x16x32_bf16(afn, bf, avn[j], 0, 0, 0);
        }
    }

    // ---- epilogue B: blend + bias, write v ----
    for (int j = 0; j < 2; ++j) {
        int col = (w * 2 + j) * 16 + l15;
        float bb = b2[col];
        for (int q = 0; q < 4; ++q) {
            int r = l4 * 4 + q;
            float v = (1.f - gs) * avn[j][q] + gs * avh[j][q] + bb;
            out[(row0 + r) * OUTC + col] = v;
        }
    }

    // ---- div: sum wave partials, blend, write col 128 ----
    if (tid < ROWS) {
        float dh = divp[0][0][tid] + divp[0][1][tid] + divp[0][2][tid] + divp[0][3][tid];
        float dn = divp[1][0][tid] + divp[1][1][tid] + divp[1][2][tid] + divp[1][3][tid];
        out[(row0 + tid) * OUTC + DX] = (1.f - gs) * dn + gs * dh;
    }
}

extern "C" void kernel_launch(void* const* d_in, const int* in_sizes, int n_in,
                              void* d_out, int out_size, void* d_ws, size_t ws_size,
                              hipStream_t stream) {
    const float* state = (const float*)d_in[0];
    const float* h     = (const float*)d_in[1];
    const float* hn    = (const float*)d_in[2];
    const float* t     = (const float*)d_in[3];
    const float* gs    = (const float*)d_in[4];
    const float* W1    = (const float*)d_in[5];
    const float* b1    = (const float*)d_in[6];
    const float* W2    = (const float*)d_in[7];
    const float* b2    = (const float*)d_in[8];
    float* out = (float*)d_out;

    // workspace layout: c (512 f32) | W1P (131072 bf16) | W2P (65536 bf16)  ~= 390 KB
    float* c   = (float*)d_ws;
    short* w1p = (short*)((char*)d_ws + 2048);
    short* w2p = (short*)((char*)d_ws + 2048 + 262144);

    prep_kernel<<<256, 256, 0, stream>>>(W1, W2, c, w1p, w2p);
    cvf_kernel<<<NB / ROWS, 256, 0, stream>>>(state, h, hn, t, gs, W1, b1, b2, c, w1p, w2p, out);
}

// Round 2
// 22.886 us; speedup vs baseline: 1.4878x; 1.4878x over previous
//
#include <hip/hip_runtime.h>
#include <hip/hip_bf16.h>

#define DX 128
#define DH 128
#define HID 512
#define NB 4096
#define ROWS 16
#define OUTC 129   // 128 v cols + 1 div col

typedef __attribute__((ext_vector_type(4))) float f32x4;
typedef __attribute__((ext_vector_type(4))) float float4v;
typedef __attribute__((ext_vector_type(8))) short bf16x8;
typedef __attribute__((ext_vector_type(4))) short bf16x4;

// RNE float -> bf16 (bit pattern in a short)
__device__ inline short f2bf(float f) {
    unsigned u = __float_as_uint(f);
    unsigned r = (u + 0x7fffu + ((u >> 16) & 1u)) >> 16;
    return (short)r;
}

__device__ inline float fast_tanh(float x) {
    float e = __expf(2.0f * x);
    float r = __builtin_amdgcn_rcpf(e + 1.0f);
    return 1.0f - 2.0f * r;
}

// -------- prep: c[k] = sum_i W1[i,k]*W2[k,i]; pack W1,W2 to bf16 B-fragment order ---
// W1P layout: [nt(32)][ks(8)][lane(64)][e(8)]  ->  W1[(ks*32 + (l>>4)*8 + e), nt*16 + (l&15)]
// W2P layout: [nt(8)][ks(16)][lane(64)][e(8)]  ->  W2[(ks*32 + (l>>4)*8 + e), nt*16 + (l&15)]
__global__ __launch_bounds__(256) void prep_kernel(
    const float* __restrict__ W1, const float* __restrict__ W2,
    float* __restrict__ c, short* __restrict__ w1p, short* __restrict__ w2p)
{
    int gid = blockIdx.x * 256 + threadIdx.x;  // 0..65535

    if (gid < HID) {
        float acc = 0.f;
        for (int i = 0; i < DX; ++i) acc += W1[i * HID + gid] * W2[gid * DX + i];
        c[gid] = acc;
    }

    for (int i = gid; i < 32 * 8 * 64 * 8; i += 65536) {   // 131072 elems, 2 iters
        int nt = i >> 12;
        int ks = (i >> 9) & 7;
        int l  = (i >> 3) & 63;
        int e  = i & 7;
        int m  = ks * 32 + ((l >> 4) << 3) + e;     // 0..255
        int n  = nt * 16 + (l & 15);                // 0..511
        w1p[i] = f2bf(W1[m * HID + n]);
    }

    if (gid < 8 * 16 * 64 * 8) {                    // 65536 elems
        int i = gid;
        int nt = i >> 13;
        int ks = (i >> 9) & 15;
        int l  = (i >> 3) & 63;
        int e  = i & 7;
        int k  = ks * 32 + ((l >> 4) << 3) + e;     // 0..511
        int n  = nt * 16 + (l & 15);                // 0..127
        w2p[i] = f2bf(W2[k * DX + n]);
    }
}

// -------- main fused kernel: 16 rows per block, 8 waves (2 waves/SIMD at 256 blocks) ----
// Wave w: GEMM1 hidden cols [w*64, w*64+64)  (4 nt-tiles)
//         GEMM2 out    cols [w*16, w*16+16)  (1 nt-tile)
__global__ __launch_bounds__(512) void cvf_kernel(
    const float* __restrict__ state, const float* __restrict__ h_,
    const float* __restrict__ hn_, const float* __restrict__ tptr,
    const float* __restrict__ gsptr, const float* __restrict__ W1,
    const float* __restrict__ b1, const float* __restrict__ b2,
    const float* __restrict__ c, const short* __restrict__ w1p,
    const short* __restrict__ w2p, float* __restrict__ out)
{
    __shared__ short xb [ROWS][DX  + 8];
    __shared__ short hb [ROWS][DH  + 8];
    __shared__ short hnb[ROWS][DH  + 8];
    __shared__ short ab_h[ROWS][HID + 8];
    __shared__ short ab_n[ROWS][HID + 8];
    __shared__ float divp[2][8][ROWS];

    const int tid  = threadIdx.x;
    const int lane = tid & 63;
    const int w    = tid >> 6;         // wave 0..7
    const int l15  = lane & 15;
    const int l4   = lane >> 4;
    const int row0 = blockIdx.x * ROWS;
    const float t  = tptr[0];
    const float gs = gsptr[0];

    // ---- prefetch (independent of staging): ks=0 B-frags + bias/t-col fold ----
    bf16x8 bpre[4];
    float base[4];
    for (int nt = 0; nt < 4; ++nt) {
        bpre[nt] = *(const bf16x8*)&w1p[(((w * 4 + nt) * 8 + 0) * 64 + lane) * 8];
        int k = w * 64 + nt * 16 + l15;
        base[nt] = b1[k] + t * W1[256 * HID + k];
    }

    // ---- stage x / h / h_null as bf16 into LDS (512 threads: 4 floats each) ----
    {
        int r  = tid >> 5;            // 0..15
        int c0 = (tid & 31) * 4;      // 0..124
        const float* sp = state + (row0 + r) * OUTC + c0;   // x = state[:, :128] (4B-aligned only)
        float4v vh = *(const float4v*)(h_  + (row0 + r) * DH + c0);  // 16B-aligned
        float4v vn = *(const float4v*)(hn_ + (row0 + r) * DH + c0);
        bf16x4 sx, sh, sn;
        for (int e = 0; e < 4; ++e) {
            sx[e] = f2bf(sp[e]);
            sh[e] = f2bf(vh[e]);
            sn[e] = f2bf(vn[e]);
        }
        *(bf16x4*)&xb [r][c0] = sx;
        *(bf16x4*)&hb [r][c0] = sh;
        *(bf16x4*)&hnb[r][c0] = sn;
    }
    __syncthreads();

    // ---- GEMM1: pre = [x|h|t] @ W1 + b1 ----
    f32x4 acc_h[4], acc_n[4];
    {
        f32x4 accx[4];
        for (int nt = 0; nt < 4; ++nt)
            accx[nt] = (f32x4){base[nt], base[nt], base[nt], base[nt]};
        {   // ks = 0 uses prefetched B-frags
            bf16x8 af = *(const bf16x8*)&xb[l15][l4 * 8];
            for (int nt = 0; nt < 4; ++nt)
                accx[nt] = __builtin_amdgcn_mfma_f32_16x16x32_bf16(af, bpre[nt], accx[nt], 0, 0, 0);
        }
        for (int ks = 1; ks < 4; ++ks) {                  // x part: K = 128
            bf16x8 af = *(const bf16x8*)&xb[l15][ks * 32 + l4 * 8];
            for (int nt = 0; nt < 4; ++nt) {
                bf16x8 bf = *(const bf16x8*)&w1p[(((w * 4 + nt) * 8 + ks) * 64 + lane) * 8];
                accx[nt] = __builtin_amdgcn_mfma_f32_16x16x32_bf16(af, bf, accx[nt], 0, 0, 0);
            }
        }
        for (int nt = 0; nt < 4; ++nt) { acc_h[nt] = accx[nt]; acc_n[nt] = accx[nt]; }
        for (int ks = 0; ks < 4; ++ks) {                  // h / h_null part: K = 128
            bf16x8 afh = *(const bf16x8*)&hb [l15][ks * 32 + l4 * 8];
            bf16x8 afn = *(const bf16x8*)&hnb[l15][ks * 32 + l4 * 8];
            for (int nt = 0; nt < 4; ++nt) {
                bf16x8 bf = *(const bf16x8*)&w1p[(((w * 4 + nt) * 8 + 4 + ks) * 64 + lane) * 8];
                acc_h[nt] = __builtin_amdgcn_mfma_f32_16x16x32_bf16(afh, bf, acc_h[nt], 0, 0, 0);
                acc_n[nt] = __builtin_amdgcn_mfma_f32_16x16x32_bf16(afn, bf, acc_n[nt], 0, 0, 0);
            }
        }
    }

    // ---- epilogue A: a = tanh(pre) -> LDS (bf16); div partials (1-a^2)*c[k] ----
    float dph[4] = {0, 0, 0, 0}, dpn[4] = {0, 0, 0, 0};
    for (int nt = 0; nt < 4; ++nt) {
        int k = w * 64 + nt * 16 + l15;                   // D-frag col = lane&15 (m89-verified)
        float ck = c[k];
        for (int q = 0; q < 4; ++q) {
            int r = l4 * 4 + q;                           // D-frag row = (lane>>4)*4 + q
            float a1 = fast_tanh(acc_h[nt][q]);
            float a2 = fast_tanh(acc_n[nt][q]);
            ab_h[r][k] = f2bf(a1);
            ab_n[r][k] = f2bf(a2);
            dph[q] += (1.f - a1 * a1) * ck;
            dpn[q] += (1.f - a2 * a2) * ck;
        }
    }
    // reduce div partials over the 16 lanes sharing l4 (xor low 4 lane bits)
    for (int q = 0; q < 4; ++q) {
        for (int m = 1; m < 16; m <<= 1) {
            dph[q] += __shfl_xor(dph[q], m, 64);
            dpn[q] += __shfl_xor(dpn[q], m, 64);
        }
    }
    if (l15 == 0) {
        for (int q = 0; q < 4; ++q) {
            divp[0][w][l4 * 4 + q] = dph[q];
            divp[1][w][l4 * 4 + q] = dpn[q];
        }
    }
    __syncthreads();

    // ---- GEMM2: v = a @ W2, wave w owns out cols [w*16, w*16+16) ----
    f32x4 avh = (f32x4){0, 0, 0, 0}, avn = (f32x4){0, 0, 0, 0};
    for (int ks = 0; ks < 16; ++ks) {
        bf16x8 afh = *(const bf16x8*)&ab_h[l15][ks * 32 + l4 * 8];
        bf16x8 afn = *(const bf16x8*)&ab_n[l15][ks * 32 + l4 * 8];
        bf16x8 bf  = *(const bf16x8*)&w2p[((w * 16 + ks) * 64 + lane) * 8];
        avh = __builtin_amdgcn_mfma_f32_16x16x32_bf16(afh, bf, avh, 0, 0, 0);
        avn = __builtin_amdgcn_mfma_f32_16x16x32_bf16(afn, bf, avn, 0, 0, 0);
    }

    // ---- epilogue B: blend + bias, write v ----
    {
        int col = w * 16 + l15;
        float bb = b2[col];
        for (int q = 0; q < 4; ++q) {
            int r = l4 * 4 + q;
            float v = (1.f - gs) * avn[q] + gs * avh[q] + bb;
            out[(row0 + r) * OUTC + col] = v;
        }
    }

    // ---- div: sum wave partials, blend, write col 128 ----
    if (tid < ROWS) {
        float dh = 0.f, dn = 0.f;
        for (int ww = 0; ww < 8; ++ww) { dh += divp[0][ww][tid]; dn += divp[1][ww][tid]; }
        out[(row0 + tid) * OUTC + DX] = (1.f - gs) * dn + gs * dh;
    }
}

extern "C" void kernel_launch(void* const* d_in, const int* in_sizes, int n_in,
                              void* d_out, int out_size, void* d_ws, size_t ws_size,
                              hipStream_t stream) {
    const float* state = (const float*)d_in[0];
    const float* h     = (const float*)d_in[1];
    const float* hn    = (const float*)d_in[2];
    const float* t     = (const float*)d_in[3];
    const float* gs    = (const float*)d_in[4];
    const float* W1    = (const float*)d_in[5];
    const float* b1    = (const float*)d_in[6];
    const float* W2    = (const float*)d_in[7];
    const float* b2    = (const float*)d_in[8];
    float* out = (float*)d_out;

    // workspace layout: c (512 f32) | W1P (131072 bf16) | W2P (65536 bf16)  ~= 390 KB
    float* c   = (float*)d_ws;
    short* w1p = (short*)((char*)d_ws + 2048);
    short* w2p = (short*)((char*)d_ws + 2048 + 262144);

    prep_kernel<<<256, 256, 0, stream>>>(W1, W2, c, w1p, w2p);
    cvf_kernel<<<NB / ROWS, 512, 0, stream>>>(state, h, hn, t, gs, W1, b1, b2, c, w1p, w2p, out);
}

// Round 3
// 18.706 us; speedup vs baseline: 1.8203x; 1.2235x over previous
//
#include <hip/hip_runtime.h>
#include <hip/hip_bf16.h>

#define DX 128
#define DH 128
#define HID 512
#define NB 4096
#define ROWS 16
#define OUTC 129   // 128 v cols + 1 div col

typedef __attribute__((ext_vector_type(4))) float f32x4;
typedef __attribute__((ext_vector_type(2))) float float2v;
typedef __attribute__((ext_vector_type(8))) short bf16x8;
typedef __attribute__((ext_vector_type(2))) short bf16x2;

// RNE float -> bf16 (bit pattern in a short)
__device__ inline short f2bf(float f) {
    unsigned u = __float_as_uint(f);
    unsigned r = (u + 0x7fffu + ((u >> 16) & 1u)) >> 16;
    return (short)r;
}

__device__ inline float fast_tanh(float x) {
    float e = __expf(2.0f * x);
    float r = __builtin_amdgcn_rcpf(e + 1.0f);
    return 1.0f - 2.0f * r;
}

// -------- prep: c[k] = sum_i W1[i,k]*W2[k,i]; pack W1,W2 to bf16 B-fragment order ---
// W1P layout: [nt(32)][ks(8)][lane(64)][e(8)]  ->  W1[(ks*32 + (l>>4)*8 + e), nt*16 + (l&15)]
// W2P layout: [nt(8)][ks(16)][lane(64)][e(8)]  ->  W2[(ks*32 + (l>>4)*8 + e), nt*16 + (l&15)]
__global__ __launch_bounds__(256) void prep_kernel(
    const float* __restrict__ W1, const float* __restrict__ W2,
    float* __restrict__ c, short* __restrict__ w1p, short* __restrict__ w2p)
{
    int gid = blockIdx.x * 256 + threadIdx.x;  // 0..65535

    // c[k]: wave-parallel dot (lane i0 handles i0 and i0+64), shuffle reduce
    if (gid < HID * 64) {                      // 32768 threads, 512 waves
        int k  = gid >> 6;
        int i0 = gid & 63;
        float p = W1[i0 * HID + k] * W2[k * DX + i0]
                + W1[(i0 + 64) * HID + k] * W2[k * DX + i0 + 64];
        for (int m = 1; m < 64; m <<= 1) p += __shfl_xor(p, m, 64);
        if (i0 == 0) c[k] = p;
    }

    for (int i = gid; i < 32 * 8 * 64 * 8; i += 65536) {   // 131072 elems, 2 iters
        int nt = i >> 12;
        int ks = (i >> 9) & 7;
        int l  = (i >> 3) & 63;
        int e  = i & 7;
        int m  = ks * 32 + ((l >> 4) << 3) + e;     // 0..255
        int n  = nt * 16 + (l & 15);                // 0..511
        w1p[i] = f2bf(W1[m * HID + n]);
    }

    if (gid < 8 * 16 * 64 * 8) {                    // 65536 elems
        int i = gid;
        int nt = i >> 13;
        int ks = (i >> 9) & 15;
        int l  = (i >> 3) & 63;
        int e  = i & 7;
        int k  = ks * 32 + ((l >> 4) << 3) + e;     // 0..511
        int n  = nt * 16 + (l & 15);                // 0..127
        w2p[i] = f2bf(W2[k * DX + n]);
    }
}

// -------- main fused kernel: 16 rows/block, 16 waves (4 waves/SIMD at 256 blocks) ----
// GEMM1: wave w owns hidden cols [w*32, w*32+32)   (2 nt-tiles)
// GEMM2: wave pair (2m, 2m+1) owns out cols [m*16, m*16+16); even wave K=0..255,
//        odd wave K=256..511; partials reduced via LDS.
__global__ __launch_bounds__(1024) void cvf_kernel(
    const float* __restrict__ state, const float* __restrict__ h_,
    const float* __restrict__ hn_, const float* __restrict__ tptr,
    const float* __restrict__ gsptr, const float* __restrict__ W1,
    const float* __restrict__ b1, const float* __restrict__ b2,
    const float* __restrict__ c, const short* __restrict__ w1p,
    const short* __restrict__ w2p, float* __restrict__ out)
{
    __shared__ short xb [ROWS][DX  + 8];
    __shared__ short hb [ROWS][DH  + 8];
    __shared__ short hnb[ROWS][DH  + 8];
    __shared__ short ab_h[ROWS][HID + 8];
    __shared__ short ab_n[ROWS][HID + 8];
    __shared__ float divp[2][16][ROWS];
    __shared__ float red[8][2][64][4];   // [pair][branch][lane][q]

    const int tid  = threadIdx.x;
    const int lane = tid & 63;
    const int w    = tid >> 6;         // wave 0..15
    const int l15  = lane & 15;
    const int l4   = lane >> 4;
    const int row0 = blockIdx.x * ROWS;
    const float t  = tptr[0];
    const float gs = gsptr[0];

    // ---- prefetch (independent of staging): ks=0 B-frags + bias/t-col fold ----
    bf16x8 bpre[2];
    float base[2];
    for (int j = 0; j < 2; ++j) {
        bpre[j] = *(const bf16x8*)&w1p[(((w * 2 + j) * 8 + 0) * 64 + lane) * 8];
        int k = w * 32 + j * 16 + l15;
        base[j] = b1[k] + t * W1[256 * HID + k];
    }

    // ---- stage x / h / h_null as bf16 into LDS (1024 threads: 2 floats each) ----
    {
        int r  = tid >> 6;            // 0..15
        int c0 = (tid & 63) * 2;      // 0..126
        const float* sp = state + (row0 + r) * OUTC + c0;   // x = state[:, :128]
        float2v vh = *(const float2v*)(h_  + (row0 + r) * DH + c0);
        float2v vn = *(const float2v*)(hn_ + (row0 + r) * DH + c0);
        bf16x2 sx, sh, sn;
        for (int e = 0; e < 2; ++e) {
            sx[e] = f2bf(sp[e]);
            sh[e] = f2bf(vh[e]);
            sn[e] = f2bf(vn[e]);
        }
        *(bf16x2*)&xb [r][c0] = sx;
        *(bf16x2*)&hb [r][c0] = sh;
        *(bf16x2*)&hnb[r][c0] = sn;
    }
    __syncthreads();

    // ---- GEMM1: pre = [x|h|t] @ W1 + b1 ----
    f32x4 acc_h[2], acc_n[2];
    {
        f32x4 accx[2];
        for (int j = 0; j < 2; ++j)
            accx[j] = (f32x4){base[j], base[j], base[j], base[j]};
        {   // ks = 0 uses prefetched B-frags
            bf16x8 af = *(const bf16x8*)&xb[l15][l4 * 8];
            for (int j = 0; j < 2; ++j)
                accx[j] = __builtin_amdgcn_mfma_f32_16x16x32_bf16(af, bpre[j], accx[j], 0, 0, 0);
        }
        for (int ks = 1; ks < 4; ++ks) {                  // x part: K = 128
            bf16x8 af = *(const bf16x8*)&xb[l15][ks * 32 + l4 * 8];
            for (int j = 0; j < 2; ++j) {
                bf16x8 bf = *(const bf16x8*)&w1p[(((w * 2 + j) * 8 + ks) * 64 + lane) * 8];
                accx[j] = __builtin_amdgcn_mfma_f32_16x16x32_bf16(af, bf, accx[j], 0, 0, 0);
            }
        }
        for (int j = 0; j < 2; ++j) { acc_h[j] = accx[j]; acc_n[j] = accx[j]; }
        for (int ks = 0; ks < 4; ++ks) {                  // h / h_null part: K = 128
            bf16x8 afh = *(const bf16x8*)&hb [l15][ks * 32 + l4 * 8];
            bf16x8 afn = *(const bf16x8*)&hnb[l15][ks * 32 + l4 * 8];
            for (int j = 0; j < 2; ++j) {
                bf16x8 bf = *(const bf16x8*)&w1p[(((w * 2 + j) * 8 + 4 + ks) * 64 + lane) * 8];
                acc_h[j] = __builtin_amdgcn_mfma_f32_16x16x32_bf16(afh, bf, acc_h[j], 0, 0, 0);
                acc_n[j] = __builtin_amdgcn_mfma_f32_16x16x32_bf16(afn, bf, acc_n[j], 0, 0, 0);
            }
        }
    }

    // ---- epilogue A: a = tanh(pre) -> LDS (bf16); div partials (1-a^2)*c[k] ----
    float dph[4] = {0, 0, 0, 0}, dpn[4] = {0, 0, 0, 0};
    for (int j = 0; j < 2; ++j) {
        int k = w * 32 + j * 16 + l15;                    // D-frag col = lane&15 (m89-verified)
        float ck = c[k];
        for (int q = 0; q < 4; ++q) {
            int r = l4 * 4 + q;                           // D-frag row = (lane>>4)*4 + q
            float a1 = fast_tanh(acc_h[j][q]);
            float a2 = fast_tanh(acc_n[j][q]);
            ab_h[r][k] = f2bf(a1);
            ab_n[r][k] = f2bf(a2);
            dph[q] += (1.f - a1 * a1) * ck;
            dpn[q] += (1.f - a2 * a2) * ck;
        }
    }
    // reduce div partials over the 16 lanes sharing l4 (xor low 4 lane bits)
    for (int q = 0; q < 4; ++q) {
        for (int m = 1; m < 16; m <<= 1) {
            dph[q] += __shfl_xor(dph[q], m, 64);
            dpn[q] += __shfl_xor(dpn[q], m, 64);
        }
    }
    if (l15 == 0) {
        for (int q = 0; q < 4; ++q) {
            divp[0][w][l4 * 4 + q] = dph[q];
            divp[1][w][l4 * 4 + q] = dpn[q];
        }
    }
    __syncthreads();

    // ---- GEMM2 (K-split): wave pair (2m,2m+1) -> out cols [m*16,m*16+16) ----
    f32x4 avh = (f32x4){0, 0, 0, 0}, avn = (f32x4){0, 0, 0, 0};
    {
        int nt2 = w >> 1;
        int ks0 = (w & 1) * 8;
        for (int ks = 0; ks < 8; ++ks) {
            bf16x8 afh = *(const bf16x8*)&ab_h[l15][(ks0 + ks) * 32 + l4 * 8];
            bf16x8 afn = *(const bf16x8*)&ab_n[l15][(ks0 + ks) * 32 + l4 * 8];
            bf16x8 bf  = *(const bf16x8*)&w2p[((nt2 * 16 + ks0 + ks) * 64 + lane) * 8];
            avh = __builtin_amdgcn_mfma_f32_16x16x32_bf16(afh, bf, avh, 0, 0, 0);
            avn = __builtin_amdgcn_mfma_f32_16x16x32_bf16(afn, bf, avn, 0, 0, 0);
        }
    }
    if (w & 1) {
        for (int q = 0; q < 4; ++q) {
            red[w >> 1][0][lane][q] = avh[q];
            red[w >> 1][1][lane][q] = avn[q];
        }
    }
    __syncthreads();

    // ---- epilogue B: even waves combine partials, blend + bias, write v ----
    if (!(w & 1)) {
        int col = (w >> 1) * 16 + l15;
        float bb = b2[col];
        for (int q = 0; q < 4; ++q) {
            int r = l4 * 4 + q;
            float vh = avh[q] + red[w >> 1][0][lane][q];
            float vn = avn[q] + red[w >> 1][1][lane][q];
            float v = (1.f - gs) * vn + gs * vh + bb;
            out[(row0 + r) * OUTC + col] = v;
        }
    }

    // ---- div: sum wave partials, blend, write col 128 ----
    if (tid < ROWS) {
        float dh = 0.f, dn = 0.f;
        for (int ww = 0; ww < 16; ++ww) { dh += divp[0][ww][tid]; dn += divp[1][ww][tid]; }
        out[(row0 + tid) * OUTC + DX] = (1.f - gs) * dn + gs * dh;
    }
}

extern "C" void kernel_launch(void* const* d_in, const int* in_sizes, int n_in,
                              void* d_out, int out_size, void* d_ws, size_t ws_size,
                              hipStream_t stream) {
    const float* state = (const float*)d_in[0];
    const float* h     = (const float*)d_in[1];
    const float* hn    = (const float*)d_in[2];
    const float* t     = (const float*)d_in[3];
    const float* gs    = (const float*)d_in[4];
    const float* W1    = (const float*)d_in[5];
    const float* b1    = (const float*)d_in[6];
    const float* W2    = (const float*)d_in[7];
    const float* b2    = (const float*)d_in[8];
    float* out = (float*)d_out;

    // workspace layout: c (512 f32) | W1P (131072 bf16) | W2P (65536 bf16)  ~= 390 KB
    float* c   = (float*)d_ws;
    short* w1p = (short*)((char*)d_ws + 2048);
    short* w2p = (short*)((char*)d_ws + 2048 + 262144);

    prep_kernel<<<256, 256, 0, stream>>>(W1, W2, c, w1p, w2p);
    cvf_kernel<<<NB / ROWS, 1024, 0, stream>>>(state, h, hn, t, gs, W1, b1, b2, c, w1p, w2p, out);
}

// Round 4
// 18.495 us; speedup vs baseline: 1.8410x; 1.0114x over previous
//
#include <hip/hip_runtime.h>
#include <hip/hip_bf16.h>

#define DX 128
#define DH 128
#define HID 512
#define NB 4096
#define ROWS 16
#define OUTC 129   // 128 v cols + 1 div col

typedef __attribute__((ext_vector_type(4))) float f32x4;
typedef __attribute__((ext_vector_type(2))) float float2v;
typedef __attribute__((ext_vector_type(8))) short bf16x8;
typedef __attribute__((ext_vector_type(2))) short bf16x2;

// RNE float -> bf16 (bit pattern in a short)
__device__ inline short f2bf(float f) {
    unsigned u = __float_as_uint(f);
    unsigned r = (u + 0x7fffu + ((u >> 16) & 1u)) >> 16;
    return (short)r;
}

__device__ inline float fast_tanh(float x) {
    float e = __expf(2.0f * x);
    float r = __builtin_amdgcn_rcpf(e + 1.0f);
    return 1.0f - 2.0f * r;
}

// -------- prep: c[k] = sum_i W1[i,k]*W2[k,i]; pack W1,W2 to bf16 B-fragment order ---
// W1P layout: [nt(32)][ks(8)][lane(64)][e(8)]  ->  W1[(ks*32 + (l>>4)*8 + e), nt*16 + (l&15)]
// W2P layout: [nt(8)][ks(16)][lane(64)][e(8)]  ->  W2[(ks*32 + (l>>4)*8 + e), nt*16 + (l&15)]
__global__ __launch_bounds__(256) void prep_kernel(
    const float* __restrict__ W1, const float* __restrict__ W2,
    float* __restrict__ c, short* __restrict__ w1p, short* __restrict__ w2p)
{
    int gid = blockIdx.x * 256 + threadIdx.x;  // 0..65535

    // c[k]: wave-parallel dot (lane i0 handles i0 and i0+64), shuffle reduce
    if (gid < HID * 64) {                      // 32768 threads, 512 waves
        int k  = gid >> 6;
        int i0 = gid & 63;
        float p = W1[i0 * HID + k] * W2[k * DX + i0]
                + W1[(i0 + 64) * HID + k] * W2[k * DX + i0 + 64];
        for (int m = 1; m < 64; m <<= 1) p += __shfl_xor(p, m, 64);
        if (i0 == 0) c[k] = p;
    }

    for (int i = gid; i < 32 * 8 * 64 * 8; i += 65536) {   // 131072 elems, 2 iters
        int nt = i >> 12;
        int ks = (i >> 9) & 7;
        int l  = (i >> 3) & 63;
        int e  = i & 7;
        int m  = ks * 32 + ((l >> 4) << 3) + e;     // 0..255
        int n  = nt * 16 + (l & 15);                // 0..511
        w1p[i] = f2bf(W1[m * HID + n]);
    }

    if (gid < 8 * 16 * 64 * 8) {                    // 65536 elems
        int i = gid;
        int nt = i >> 13;
        int ks = (i >> 9) & 15;
        int l  = (i >> 3) & 63;
        int e  = i & 7;
        int k  = ks * 32 + ((l >> 4) << 3) + e;     // 0..511
        int n  = nt * 16 + (l & 15);                // 0..127
        w2p[i] = f2bf(W2[k * DX + n]);
    }
}

// -------- main fused kernel: 16 rows/block, 16 waves (4 waves/SIMD at 256 blocks) ----
// GEMM1: wave w owns hidden cols [w*32, w*32+32)   (2 nt-tiles)
// GEMM2: wave pair (2m, 2m+1) owns out cols [m*16, m*16+16); even wave K=0..255,
//        odd wave K=256..511; partials reduced via LDS.
__global__ __launch_bounds__(1024) void cvf_kernel(
    const float* __restrict__ state, const float* __restrict__ h_,
    const float* __restrict__ hn_, const float* __restrict__ tptr,
    const float* __restrict__ gsptr, const float* __restrict__ W1,
    const float* __restrict__ b1, const float* __restrict__ b2,
    const float* __restrict__ c, const short* __restrict__ w1p,
    const short* __restrict__ w2p, float* __restrict__ out)
{
    __shared__ short xb [ROWS][DX  + 8];
    __shared__ short hb [ROWS][DH  + 8];
    __shared__ short hnb[ROWS][DH  + 8];
    __shared__ short ab_h[ROWS][HID + 8];
    __shared__ short ab_n[ROWS][HID + 8];
    __shared__ float divp[2][16][ROWS];
    __shared__ float red[8][2][64][4];   // [pair][branch][lane][q]

    const int tid  = threadIdx.x;
    const int lane = tid & 63;
    const int w    = tid >> 6;         // wave 0..15
    const int l15  = lane & 15;
    const int l4   = lane >> 4;
    const int row0 = blockIdx.x * ROWS;
    const float t  = tptr[0];
    const float gs = gsptr[0];

    // ---- prefetch (independent of staging): ALL 8 x-part B-frags + bias/t-col fold ----
    bf16x8 bx[2][4];
    float base[2];
    #pragma unroll
    for (int j = 0; j < 2; ++j) {
        #pragma unroll
        for (int ks = 0; ks < 4; ++ks)
            bx[j][ks] = *(const bf16x8*)&w1p[(((w * 2 + j) * 8 + ks) * 64 + lane) * 8];
        int k = w * 32 + j * 16 + l15;
        base[j] = b1[k] + t * W1[256 * HID + k];
    }

    // ---- stage x / h / h_null as bf16 into LDS (1024 threads: 2 floats each) ----
    {
        int r  = tid >> 6;            // 0..15
        int c0 = (tid & 63) * 2;      // 0..126
        const float* sp = state + (row0 + r) * OUTC + c0;   // x = state[:, :128]
        float2v vh = *(const float2v*)(h_  + (row0 + r) * DH + c0);
        float2v vn = *(const float2v*)(hn_ + (row0 + r) * DH + c0);
        bf16x2 sx, sh, sn;
        for (int e = 0; e < 2; ++e) {
            sx[e] = f2bf(sp[e]);
            sh[e] = f2bf(vh[e]);
            sn[e] = f2bf(vn[e]);
        }
        *(bf16x2*)&xb [r][c0] = sx;
        *(bf16x2*)&hb [r][c0] = sh;
        *(bf16x2*)&hnb[r][c0] = sn;
    }
    __syncthreads();

    // ---- GEMM1: pre = [x|h|t] @ W1 + b1 ----
    f32x4 acc_h[2], acc_n[2];
    {
        // batch-load all 4 x A-frags from LDS
        bf16x8 ax[4];
        #pragma unroll
        for (int ks = 0; ks < 4; ++ks)
            ax[ks] = *(const bf16x8*)&xb[l15][ks * 32 + l4 * 8];

        f32x4 accx[2];
        #pragma unroll
        for (int j = 0; j < 2; ++j)
            accx[j] = (f32x4){base[j], base[j], base[j], base[j]};
        #pragma unroll
        for (int ks = 0; ks < 4; ++ks)
            #pragma unroll
            for (int j = 0; j < 2; ++j)
                accx[j] = __builtin_amdgcn_mfma_f32_16x16x32_bf16(ax[ks], bx[j][ks], accx[j], 0, 0, 0);

        // batch-issue all 8 h-part B-frags + all 8 h/hn A-frags
        bf16x8 bh[2][4];
        #pragma unroll
        for (int j = 0; j < 2; ++j)
            #pragma unroll
            for (int ks = 0; ks < 4; ++ks)
                bh[j][ks] = *(const bf16x8*)&w1p[(((w * 2 + j) * 8 + 4 + ks) * 64 + lane) * 8];
        bf16x8 ah[4], an[4];
        #pragma unroll
        for (int ks = 0; ks < 4; ++ks) {
            ah[ks] = *(const bf16x8*)&hb [l15][ks * 32 + l4 * 8];
            an[ks] = *(const bf16x8*)&hnb[l15][ks * 32 + l4 * 8];
        }

        #pragma unroll
        for (int j = 0; j < 2; ++j) { acc_h[j] = accx[j]; acc_n[j] = accx[j]; }
        #pragma unroll
        for (int ks = 0; ks < 4; ++ks)
            #pragma unroll
            for (int j = 0; j < 2; ++j) {
                acc_h[j] = __builtin_amdgcn_mfma_f32_16x16x32_bf16(ah[ks], bh[j][ks], acc_h[j], 0, 0, 0);
                acc_n[j] = __builtin_amdgcn_mfma_f32_16x16x32_bf16(an[ks], bh[j][ks], acc_n[j], 0, 0, 0);
            }
    }

    // ---- prefetch GEMM2 B-frags NOW: latency hides under epilogue A ----
    const int nt2 = w >> 1;
    const int ks0 = (w & 1) * 8;
    bf16x8 b2f[8];
    #pragma unroll
    for (int ks = 0; ks < 8; ++ks)
        b2f[ks] = *(const bf16x8*)&w2p[((nt2 * 16 + ks0 + ks) * 64 + lane) * 8];

    // ---- epilogue A: a = tanh(pre) -> LDS (bf16); div partials (1-a^2)*c[k] ----
    float dph[4] = {0, 0, 0, 0}, dpn[4] = {0, 0, 0, 0};
    for (int j = 0; j < 2; ++j) {
        int k = w * 32 + j * 16 + l15;                    // D-frag col = lane&15 (m89-verified)
        float ck = c[k];
        for (int q = 0; q < 4; ++q) {
            int r = l4 * 4 + q;                           // D-frag row = (lane>>4)*4 + q
            float a1 = fast_tanh(acc_h[j][q]);
            float a2 = fast_tanh(acc_n[j][q]);
            ab_h[r][k] = f2bf(a1);
            ab_n[r][k] = f2bf(a2);
            dph[q] += (1.f - a1 * a1) * ck;
            dpn[q] += (1.f - a2 * a2) * ck;
        }
    }
    // reduce div partials over the 16 lanes sharing l4 (xor low 4 lane bits)
    for (int q = 0; q < 4; ++q) {
        for (int m = 1; m < 16; m <<= 1) {
            dph[q] += __shfl_xor(dph[q], m, 64);
            dpn[q] += __shfl_xor(dpn[q], m, 64);
        }
    }
    if (l15 == 0) {
        for (int q = 0; q < 4; ++q) {
            divp[0][w][l4 * 4 + q] = dph[q];
            divp[1][w][l4 * 4 + q] = dpn[q];
        }
    }
    __syncthreads();

    // ---- GEMM2 (K-split): wave pair (2m,2m+1) -> out cols [m*16,m*16+16) ----
    f32x4 avh = (f32x4){0, 0, 0, 0}, avn = (f32x4){0, 0, 0, 0};
    #pragma unroll
    for (int ks = 0; ks < 8; ++ks) {
        bf16x8 afh = *(const bf16x8*)&ab_h[l15][(ks0 + ks) * 32 + l4 * 8];
        bf16x8 afn = *(const bf16x8*)&ab_n[l15][(ks0 + ks) * 32 + l4 * 8];
        avh = __builtin_amdgcn_mfma_f32_16x16x32_bf16(afh, b2f[ks], avh, 0, 0, 0);
        avn = __builtin_amdgcn_mfma_f32_16x16x32_bf16(afn, b2f[ks], avn, 0, 0, 0);
    }
    if (w & 1) {
        for (int q = 0; q < 4; ++q) {
            red[w >> 1][0][lane][q] = avh[q];
            red[w >> 1][1][lane][q] = avn[q];
        }
    }
    __syncthreads();

    // ---- epilogue B: even waves combine partials, blend + bias, write v ----
    if (!(w & 1)) {
        int col = (w >> 1) * 16 + l15;
        float bb = b2[col];
        for (int q = 0; q < 4; ++q) {
            int r = l4 * 4 + q;
            float vh = avh[q] + red[w >> 1][0][lane][q];
            float vn = avn[q] + red[w >> 1][1][lane][q];
            float v = (1.f - gs) * vn + gs * vh + bb;
            out[(row0 + r) * OUTC + col] = v;
        }
    }

    // ---- div: sum wave partials, blend, write col 128 ----
    if (tid < ROWS) {
        float dh = 0.f, dn = 0.f;
        for (int ww = 0; ww < 16; ++ww) { dh += divp[0][ww][tid]; dn += divp[1][ww][tid]; }
        out[(row0 + tid) * OUTC + DX] = (1.f - gs) * dn + gs * dh;
    }
}

extern "C" void kernel_launch(void* const* d_in, const int* in_sizes, int n_in,
                              void* d_out, int out_size, void* d_ws, size_t ws_size,
                              hipStream_t stream) {
    const float* state = (const float*)d_in[0];
    const float* h     = (const float*)d_in[1];
    const float* hn    = (const float*)d_in[2];
    const float* t     = (const float*)d_in[3];
    const float* gs    = (const float*)d_in[4];
    const float* W1    = (const float*)d_in[5];
    const float* b1    = (const float*)d_in[6];
    const float* W2    = (const float*)d_in[7];
    const float* b2    = (const float*)d_in[8];
    float* out = (float*)d_out;

    // workspace layout: c (512 f32) | W1P (131072 bf16) | W2P (65536 bf16)  ~= 390 KB
    float* c   = (float*)d_ws;
    short* w1p = (short*)((char*)d_ws + 2048);
    short* w2p = (short*)((char*)d_ws + 2048 + 262144);

    prep_kernel<<<256, 256, 0, stream>>>(W1, W2, c, w1p, w2p);
    cvf_kernel<<<NB / ROWS, 1024, 0, stream>>>(state, h, hn, t, gs, W1, b1, b2, c, w1p, w2p, out);
}